// Round 5
// baseline (134.947 us; speedup 1.0000x reference)
//
#include <hip/hip_runtime.h>
#include <cstdint>

#define NB    128
#define NCIN  1024
#define NCOUT 1024
#define NHID  256
#define NHW   1024   // 32*32 spatial elements per (b, c)

typedef float f32x4 __attribute__((ext_vector_type(4)));

// ---------------------------------------------------------------------------
// Kernel 1: global average pool — the 512 MiB roofline. One block per 16
// rows; wave w owns rows w*4..w*4+3; lane reads 4×16B (plain temporal loads:
// let L2 aggregate HBM bursts), pairwise f32 per-lane partial -> padded LDS
// -> one barrier -> 4-value f64 combine + 4-step shfl_xor tree per row.
// ---------------------------------------------------------------------------
__global__ __launch_bounds__(256) void gap_kernel(const float* __restrict__ in,
                                                  float* __restrict__ x) {
    __shared__ float part[16][65];   // stride 65: conflict-free write & read
    const int w    = threadIdx.x >> 6;
    const int lane = threadIdx.x & 63;
    const int rowBase = blockIdx.x * 16;
    const f32x4* base = reinterpret_cast<const f32x4*>(in);

#pragma unroll
    for (int r = 0; r < 4; ++r) {
        const f32x4* p = base + (size_t)(rowBase + w * 4 + r) * (NHW / 4);
        f32x4 v0 = p[lane];
        f32x4 v1 = p[lane + 64];
        f32x4 v2 = p[lane + 128];
        f32x4 v3 = p[lane + 192];
        float t0 = (v0.x + v0.y) + (v0.z + v0.w);
        float t1 = (v1.x + v1.y) + (v1.z + v1.w);
        float t2 = (v2.x + v2.y) + (v2.z + v2.w);
        float t3 = (v3.x + v3.y) + (v3.z + v3.w);
        part[w * 4 + r][lane] = (t0 + t1) + (t2 + t3);
    }
    __syncthreads();

    // Combine: 16 threads per row; each sums 4 partials in f64, then a
    // 4-step xor tree within its 16-thread group.
    const int row = threadIdx.x >> 4;
    const int seg = threadIdx.x & 15;
    double s = ((double)part[row][seg * 4 + 0] + (double)part[row][seg * 4 + 1])
             + ((double)part[row][seg * 4 + 2] + (double)part[row][seg * 4 + 3]);
    s += __shfl_xor(s, 1, 64);
    s += __shfl_xor(s, 2, 64);
    s += __shfl_xor(s, 4, 64);
    s += __shfl_xor(s, 8, 64);
    if (seg == 0) x[rowBase + row] = (float)(s * (1.0 / 1024.0));
}

// ---------------------------------------------------------------------------
// Kernel 2: y = relu(x @ fc1_w^T + fc1_b). 1024 blocks: (b, 8 h-groups of 32).
// 256 threads = 32 h × 8 c-splits (chain length 32). x row staged as padded
// float4 LDS xs4[8][33] -> conflict-free ds_read_b128 broadcasts. 8-way
// partial combine via __shfl_xor (f64).
// ---------------------------------------------------------------------------
__global__ __launch_bounds__(256) void fc1_kernel(const float* __restrict__ x,
                                                  const float* __restrict__ w1,
                                                  const float* __restrict__ b1,
                                                  float* __restrict__ y) {
    __shared__ float4 xs4[8][33];
    const int b  = blockIdx.x >> 3;
    const int ho = blockIdx.x & 7;
    const int t  = threadIdx.x;

    {
        float4 v = reinterpret_cast<const float4*>(x + (size_t)b * NCIN)[t];
        xs4[t >> 5][t & 31] = v;
    }
    __syncthreads();

    const int hl = t >> 3;          // 0..31: h within group
    const int cs = t & 7;           // 0..7: c-split
    const int h  = ho * 32 + hl;
    const float4* w = reinterpret_cast<const float4*>(w1 + (size_t)h * NCIN + cs * 128);
    double a0 = 0.0, a1 = 0.0, a2 = 0.0, a3 = 0.0;
#pragma unroll
    for (int i = 0; i < 32; ++i) {
        float4 wv = w[i];
        float4 xv = xs4[cs][i];
        a0 += (double)wv.x * (double)xv.x;
        a1 += (double)wv.y * (double)xv.y;
        a2 += (double)wv.z * (double)xv.z;
        a3 += (double)wv.w * (double)xv.w;
    }
    double s = (a0 + a1) + (a2 + a3);
    s += __shfl_xor(s, 1, 64);
    s += __shfl_xor(s, 2, 64);
    s += __shfl_xor(s, 4, 64);
    if (cs == 0) {
        double v = s + (double)b1[h];
        y[(size_t)b * NHID + h] = (float)(v > 0.0 ? v : 0.0);
    }
}

// ---------------------------------------------------------------------------
// Kernel 3: g = y @ fc2_w^T + fc2_b + noise; v1 = clip(1.2*sig(g)-0.1,0,1);
// v2 = (g>0); out = row-swapped ? v2 : v1. 1024 blocks: (b, 8 j-groups of
// 128). 256 threads = 128 j × 2 c-halves, pair combine via __shfl_xor(1).
// ---------------------------------------------------------------------------
__global__ __launch_bounds__(256) void fc2_kernel(const float* __restrict__ y,
                                                  const float* __restrict__ w2,
                                                  const float* __restrict__ b2,
                                                  const float* __restrict__ noise,
                                                  const int* __restrict__ swap_idx,
                                                  int n_swap,
                                                  float* __restrict__ out) {
    __shared__ float ys[NHID];
    __shared__ int flag;
    const int b  = blockIdx.x >> 3;
    const int jo = blockIdx.x & 7;
    const int t  = threadIdx.x;

    if (t == 0) flag = 0;
    ys[t] = y[(size_t)b * NHID + t];
    __syncthreads();
    for (int i = t; i < n_swap; i += 256)
        if (swap_idx[i] == b) flag = 1;   // benign race: same value
    __syncthreads();
    const bool sw = (flag != 0);

    const int jl = t >> 1;          // 0..127
    const int ch = t & 1;           // 0..1
    const int j  = jo * 128 + jl;
    const float4* w  = reinterpret_cast<const float4*>(w2 + (size_t)j * NHID + ch * 128);
    const float*  yp = ys + ch * 128;
    double a0 = 0.0, a1 = 0.0, a2 = 0.0, a3 = 0.0;
#pragma unroll
    for (int i = 0; i < 32; ++i) {
        float4 wv = w[i];
        a0 += (double)wv.x * (double)yp[4 * i + 0];
        a1 += (double)wv.y * (double)yp[4 * i + 1];
        a2 += (double)wv.z * (double)yp[4 * i + 2];
        a3 += (double)wv.w * (double)yp[4 * i + 3];
    }
    double s = (a0 + a1) + (a2 + a3);
    s += __shfl_xor(s, 1, 64);
    if (ch == 0) {
        double g = s + (double)b2[j] + (double)noise[(size_t)b * NCOUT + j];
        float gf  = (float)g;
        float sig = 1.0f / (1.0f + __expf(-gf));
        float v1  = fminf(fmaxf(1.2f * sig - 0.1f, 0.0f), 1.0f);
        float v2  = (g > 0.0) ? 1.0f : 0.0f;
        out[(size_t)b * NCOUT + j] = sw ? v2 : v1;
    }
}

extern "C" void kernel_launch(void* const* d_in, const int* in_sizes, int n_in,
                              void* d_out, int out_size, void* d_ws, size_t ws_size,
                              hipStream_t stream) {
    const float* input = (const float*)d_in[0];   // [128,1024,32,32]
    const float* fc1_w = (const float*)d_in[1];   // [256,1024]
    const float* fc1_b = (const float*)d_in[2];   // [256]
    const float* fc2_w = (const float*)d_in[3];   // [1024,256]
    const float* fc2_b = (const float*)d_in[4];   // [1024]
    const float* noise = (const float*)d_in[5];   // [128,1024]
    const int*   swap  = (const int*)d_in[6];     // [512]
    const int n_swap = in_sizes[6];

    float* x = (float*)d_ws;          // [128,1024]  = 512 KiB
    float* y = x + NB * NCIN;         // [128,256]   = 128 KiB

    gap_kernel<<<(NB * NCIN) / 16, 256, 0, stream>>>(input, x);   // 8192 blocks
    fc1_kernel<<<NB * 8, 256, 0, stream>>>(x, fc1_w, fc1_b, y);
    fc2_kernel<<<NB * 8, 256, 0, stream>>>(y, fc2_w, fc2_b, noise, swap, n_swap,
                                           (float*)d_out);
}

// Round 6
// 120.469 us; speedup vs baseline: 1.1202x; 1.1202x over previous
//
#include <hip/hip_runtime.h>
#include <cstdint>

#define NB    128
#define NCIN  1024
#define NCOUT 1024
#define NHID  256
#define NHW   1024   // 32*32 spatial elements per (b, c)

typedef float f32x4 __attribute__((ext_vector_type(4)));

// ---------------------------------------------------------------------------
// Kernel 1: global average pool — the 512 MiB roofline. One block per 16
// rows; wave w owns rows w*4..w*4+3. All 16 nontemporal 16B loads issued
// up-front into registers (touch-once data: nt keeps it out of L2 — measured
// +13% vs temporal in R5), then pairwise-f32 partials -> padded LDS -> one
// barrier -> per-row 4-value f64 combine + 4-step shfl_xor tree (f64 for
// downstream g-sign accuracy).
// ---------------------------------------------------------------------------
__global__ __launch_bounds__(256) void gap_kernel(const float* __restrict__ in,
                                                  float* __restrict__ x) {
    __shared__ float part[16][65];   // stride 65: conflict-free write & read
    const int w    = threadIdx.x >> 6;
    const int lane = threadIdx.x & 63;
    const int rowBase = blockIdx.x * 16;
    const f32x4* base = reinterpret_cast<const f32x4*>(in);

    f32x4 v[4][4];
#pragma unroll
    for (int r = 0; r < 4; ++r) {
        const f32x4* p = base + (size_t)(rowBase + w * 4 + r) * (NHW / 4);
#pragma unroll
        for (int k = 0; k < 4; ++k)
            v[r][k] = __builtin_nontemporal_load(p + lane + 64 * k);
    }
#pragma unroll
    for (int r = 0; r < 4; ++r) {
        float t0 = (v[r][0].x + v[r][0].y) + (v[r][0].z + v[r][0].w);
        float t1 = (v[r][1].x + v[r][1].y) + (v[r][1].z + v[r][1].w);
        float t2 = (v[r][2].x + v[r][2].y) + (v[r][2].z + v[r][2].w);
        float t3 = (v[r][3].x + v[r][3].y) + (v[r][3].z + v[r][3].w);
        part[w * 4 + r][lane] = (t0 + t1) + (t2 + t3);
    }
    __syncthreads();

    const int row = threadIdx.x >> 4;
    const int seg = threadIdx.x & 15;
    double s = ((double)part[row][seg * 4 + 0] + (double)part[row][seg * 4 + 1])
             + ((double)part[row][seg * 4 + 2] + (double)part[row][seg * 4 + 3]);
    s += __shfl_xor(s, 1, 64);
    s += __shfl_xor(s, 2, 64);
    s += __shfl_xor(s, 4, 64);
    s += __shfl_xor(s, 8, 64);
    if (seg == 0) x[rowBase + row] = (float)(s * (1.0 / 1024.0));
}

// ---------------------------------------------------------------------------
// Kernel 2: y = relu(x @ fc1_w^T + fc1_b). 1024 blocks: (b, 8 h-groups of 32).
// 256 threads = 32 h × 8 c-splits (chain length 32). x row staged as padded
// float4 LDS xs4[8][33] -> conflict-free ds_read_b128 broadcasts. 8-way
// partial combine via __shfl_xor (f64).
// ---------------------------------------------------------------------------
__global__ __launch_bounds__(256) void fc1_kernel(const float* __restrict__ x,
                                                  const float* __restrict__ w1,
                                                  const float* __restrict__ b1,
                                                  float* __restrict__ y) {
    __shared__ float4 xs4[8][33];
    const int b  = blockIdx.x >> 3;
    const int ho = blockIdx.x & 7;
    const int t  = threadIdx.x;

    {
        float4 v = reinterpret_cast<const float4*>(x + (size_t)b * NCIN)[t];
        xs4[t >> 5][t & 31] = v;
    }
    __syncthreads();

    const int hl = t >> 3;          // 0..31: h within group
    const int cs = t & 7;           // 0..7: c-split
    const int h  = ho * 32 + hl;
    const float4* w = reinterpret_cast<const float4*>(w1 + (size_t)h * NCIN + cs * 128);
    double a0 = 0.0, a1 = 0.0, a2 = 0.0, a3 = 0.0;
#pragma unroll
    for (int i = 0; i < 32; ++i) {
        float4 wv = w[i];
        float4 xv = xs4[cs][i];
        a0 += (double)wv.x * (double)xv.x;
        a1 += (double)wv.y * (double)xv.y;
        a2 += (double)wv.z * (double)xv.z;
        a3 += (double)wv.w * (double)xv.w;
    }
    double s = (a0 + a1) + (a2 + a3);
    s += __shfl_xor(s, 1, 64);
    s += __shfl_xor(s, 2, 64);
    s += __shfl_xor(s, 4, 64);
    if (cs == 0) {
        double v = s + (double)b1[h];
        y[(size_t)b * NHID + h] = (float)(v > 0.0 ? v : 0.0);
    }
}

// ---------------------------------------------------------------------------
// Kernel 3: g = y @ fc2_w^T + fc2_b + noise; v1 = clip(1.2*sig(g)-0.1,0,1);
// v2 = (g>0); out = row-swapped ? v2 : v1. 1024 blocks: (b, 8 j-groups of
// 128). 256 threads = 128 j × 2 c-halves, pair combine via __shfl_xor(1).
// ---------------------------------------------------------------------------
__global__ __launch_bounds__(256) void fc2_kernel(const float* __restrict__ y,
                                                  const float* __restrict__ w2,
                                                  const float* __restrict__ b2,
                                                  const float* __restrict__ noise,
                                                  const int* __restrict__ swap_idx,
                                                  int n_swap,
                                                  float* __restrict__ out) {
    __shared__ float ys[NHID];
    __shared__ int flag;
    const int b  = blockIdx.x >> 3;
    const int jo = blockIdx.x & 7;
    const int t  = threadIdx.x;

    if (t == 0) flag = 0;
    ys[t] = y[(size_t)b * NHID + t];
    __syncthreads();
    for (int i = t; i < n_swap; i += 256)
        if (swap_idx[i] == b) flag = 1;   // benign race: same value
    __syncthreads();
    const bool sw = (flag != 0);

    const int jl = t >> 1;          // 0..127
    const int ch = t & 1;           // 0..1
    const int j  = jo * 128 + jl;
    const float4* w  = reinterpret_cast<const float4*>(w2 + (size_t)j * NHID + ch * 128);
    const float*  yp = ys + ch * 128;
    double a0 = 0.0, a1 = 0.0, a2 = 0.0, a3 = 0.0;
#pragma unroll
    for (int i = 0; i < 32; ++i) {
        float4 wv = w[i];
        a0 += (double)wv.x * (double)yp[4 * i + 0];
        a1 += (double)wv.y * (double)yp[4 * i + 1];
        a2 += (double)wv.z * (double)yp[4 * i + 2];
        a3 += (double)wv.w * (double)yp[4 * i + 3];
    }
    double s = (a0 + a1) + (a2 + a3);
    s += __shfl_xor(s, 1, 64);
    if (ch == 0) {
        double g = s + (double)b2[j] + (double)noise[(size_t)b * NCOUT + j];
        float gf  = (float)g;
        float sig = 1.0f / (1.0f + __expf(-gf));
        float v1  = fminf(fmaxf(1.2f * sig - 0.1f, 0.0f), 1.0f);
        float v2  = (g > 0.0) ? 1.0f : 0.0f;
        out[(size_t)b * NCOUT + j] = sw ? v2 : v1;
    }
}

extern "C" void kernel_launch(void* const* d_in, const int* in_sizes, int n_in,
                              void* d_out, int out_size, void* d_ws, size_t ws_size,
                              hipStream_t stream) {
    const float* input = (const float*)d_in[0];   // [128,1024,32,32]
    const float* fc1_w = (const float*)d_in[1];   // [256,1024]
    const float* fc1_b = (const float*)d_in[2];   // [256]
    const float* fc2_w = (const float*)d_in[3];   // [1024,256]
    const float* fc2_b = (const float*)d_in[4];   // [1024]
    const float* noise = (const float*)d_in[5];   // [128,1024]
    const int*   swap  = (const int*)d_in[6];     // [512]
    const int n_swap = in_sizes[6];

    float* x = (float*)d_ws;          // [128,1024]  = 512 KiB
    float* y = x + NB * NCIN;         // [128,256]   = 128 KiB

    gap_kernel<<<(NB * NCIN) / 16, 256, 0, stream>>>(input, x);   // 8192 blocks
    fc1_kernel<<<NB * 8, 256, 0, stream>>>(x, fc1_w, fc1_b, y);
    fc2_kernel<<<NB * 8, 256, 0, stream>>>(y, fc2_w, fc2_b, noise, swap, n_swap,
                                           (float*)d_out);
}